// Round 3
// baseline (203.080 us; speedup 1.0000x reference)
//
#include <hip/hip_runtime.h>
#include <hip/hip_bf16.h>

#define Bn 64
#define Tn 512
#define Dn 512
#define Hn 128
#define BT (Bn*Tn)

typedef unsigned short u16;
typedef unsigned long long u64;
typedef __attribute__((ext_vector_type(8))) short bf16x8;
typedef __attribute__((ext_vector_type(4))) float f32x4;

__device__ __forceinline__ u16 f2bf(float f) {
  union { float f; unsigned u; } v; v.f = f;
  unsigned r = (v.u + 0x7FFFu + ((v.u >> 16) & 1u)) >> 16;
  return (u16)r;
}

// async global->LDS, 16B/lane; LDS dest = wave-uniform base (+lane*16 by HW)
__device__ __forceinline__ void gload16(const void* g, void* lds) {
  __builtin_amdgcn_global_load_lds(
      (const __attribute__((address_space(1))) unsigned int*)g,
      (__attribute__((address_space(3))) unsigned int*)lds, 16, 0, 0);
}

// ---------- conversions ----------
__global__ __launch_bounds__(256) void conv_f2b(const float4* __restrict__ in,
                                                ushort4* __restrict__ out) {
  int idx = blockIdx.x * 256 + threadIdx.x;
  float4 v = in[idx];
  ushort4 o; o.x = f2bf(v.x); o.y = f2bf(v.y); o.z = f2bf(v.z); o.w = f2bf(v.w);
  out[idx] = o;
}

// coalesced LDS-tiled transpose: dagT[i*T+k] = bf16(dag[k*T+i])
__global__ __launch_bounds__(256) void dag_tr(const float* __restrict__ dag,
                                              u16* __restrict__ dagT) {
  __shared__ float s[64][65];
  int bx = blockIdx.x & 7, by = blockIdx.x >> 3;
  int r0 = by * 64, c0 = bx * 64;
  int t = threadIdx.x;
  int c4 = t & 15, rr = t >> 4;
#pragma unroll
  for (int q = 0; q < 4; ++q) {
    int r = rr + q * 16;
    float4 v = *(const float4*)&dag[(size_t)(r0 + r) * Tn + c0 + c4 * 4];
    s[c4 * 4 + 0][r] = v.x; s[c4 * 4 + 1][r] = v.y;
    s[c4 * 4 + 2][r] = v.z; s[c4 * 4 + 3][r] = v.w;
  }
  __syncthreads();
#pragma unroll
  for (int q = 0; q < 4; ++q) {
    int il = rr + q * 16;
    ushort4 o;
    o.x = f2bf(s[il][c4 * 4 + 0]); o.y = f2bf(s[il][c4 * 4 + 1]);
    o.z = f2bf(s[il][c4 * 4 + 2]); o.w = f2bf(s[il][c4 * 4 + 3]);
    *(ushort4*)&dagT[(size_t)(c0 + il) * Tn + r0 + c4 * 4] = o;
  }
}

// bits[i*8+w] bit j = (dagT[i*T + w*64 + j] != 0)
__global__ __launch_bounds__(256) void dag_bits(const u16* __restrict__ dagT,
                                                u64* __restrict__ bits) {
  int idx = blockIdx.x * 256 + threadIdx.x;
  int i = idx >> 3, w = idx & 7;
  const u16* p = dagT + (size_t)i * Tn + w * 64;
  u64 m = 0;
#pragma unroll
  for (int j = 0; j < 64; ++j) m |= (u64)(p[j] != 0) << j;
  bits[idx] = m;
}

// ---------- 128x128-tile GEMM core (BK=64), 256 threads ----------
__device__ __forceinline__ void gemm_core(const u16* __restrict__ A0, int lda,
                                          const u16* __restrict__ B0, int ldb,
                                          int K, u16* sm, f32x4 (&acc)[4][4]) {
  const int tid = threadIdx.x;
  const int lane = tid & 63, wave = tid >> 6;
  const int wr = wave >> 1, wc = wave & 1;
  const int kcb = (lane >> 4) * 16;
  const int arow = wr * 64 + (lane & 15);
  const int brow = wc * 64 + (lane & 15);
  const char* Ab = (const char*)A0;
  const char* Bb = (const char*)B0;
  char* smb = (char*)sm;

  for (int kt = 0; kt < K; kt += 64) {
#pragma unroll
    for (int q = 0; q < 4; ++q) {
      int flat = wave * 4096 + q * 1024 + lane * 16;
      int row = flat >> 7, colb = flat & 127;
      gload16(Ab + (size_t)row * (lda * 2) + kt * 2 + colb,
              smb + wave * 4096 + q * 1024);
      gload16(Bb + (size_t)row * (ldb * 2) + kt * 2 + colb,
              smb + 16384 + wave * 4096 + q * 1024);
    }
    __syncthreads();
    bf16x8 af[4][2], bfr[4][2];
#pragma unroll
    for (int m = 0; m < 4; ++m)
#pragma unroll
      for (int kk = 0; kk < 2; ++kk) {
        af[m][kk] = *(const bf16x8*)(smb + (arow + m * 16) * 128 + kk * 64 + kcb);
        bfr[m][kk] = *(const bf16x8*)(smb + 16384 + (brow + m * 16) * 128 + kk * 64 + kcb);
      }
#pragma unroll
    for (int kk = 0; kk < 2; ++kk)
#pragma unroll
      for (int m = 0; m < 4; ++m)
#pragma unroll
        for (int n = 0; n < 4; ++n)
          acc[m][n] = __builtin_amdgcn_mfma_f32_16x16x32_bf16(af[m][kk], bfr[n][kk],
                                                              acc[m][n], 0, 0, 0);
    __syncthreads();
  }
}

// ---------- stage 1: K,Q,V = swish(X W^T + b), one pass over X ----------
// grid BT/128, 512 threads (8 waves: wr in {0,1}, wc in {0..3}).
__global__ __launch_bounds__(512, 2) void qkv3(
    const u16* __restrict__ Xb, const u16* __restrict__ Wcat,
    const float* __restrict__ bk, const float* __restrict__ bq,
    const float* __restrict__ bv,
    u16* __restrict__ Kb, u16* __restrict__ QT, u16* __restrict__ VT) {
  __shared__ u16 sm[32768];   // 64KB: A(16KB) | Bk | Bq | Bv
  int m0 = blockIdx.x * 128;
  int tid = threadIdx.x, lane = tid & 63, wave = tid >> 6;
  int wr = wave >> 2, wc = wave & 3;
  int col0 = lane & 15, rg = lane >> 4, kcb = rg * 16;
  f32x4 acc[3][4][2] = {};
  const char* Ab = (const char*)(Xb + (size_t)m0 * Dn);
  const char* Wb = (const char*)Wcat;
  char* smb = (char*)sm;

  for (int kt = 0; kt < Dn; kt += 64) {
#pragma unroll
    for (int q = 0; q < 2; ++q) {
      int ch = wave * 2 + q;
      int flat = ch * 1024 + lane * 16;
      int row = flat >> 7, colb = flat & 127;
      gload16(Ab + (size_t)row * 1024 + (kt << 1) + colb, smb + ch * 1024);
    }
#pragma unroll
    for (int q = 0; q < 6; ++q) {
      int c2 = wave * 6 + q;
      int which = c2 >> 4, idx = c2 & 15;
      int flat = idx * 1024 + lane * 16;
      int row = flat >> 7, colb = flat & 127;
      gload16(Wb + (size_t)which * 131072 + (size_t)row * 1024 + (kt << 1) + colb,
              smb + 16384 + which * 16384 + idx * 1024);
    }
    __syncthreads();
    bf16x8 af[4][2];
#pragma unroll
    for (int m = 0; m < 4; ++m)
#pragma unroll
      for (int kk = 0; kk < 2; ++kk)
        af[m][kk] = *(const bf16x8*)(smb + (wr * 64 + m * 16 + col0) * 128 + kk * 64 + kcb);
#pragma unroll
    for (int which = 0; which < 3; ++which) {
      bf16x8 bfr[2][2];
#pragma unroll
      for (int n = 0; n < 2; ++n)
#pragma unroll
        for (int kk = 0; kk < 2; ++kk)
          bfr[n][kk] = *(const bf16x8*)(smb + 16384 + which * 16384 +
                                        (wc * 32 + n * 16 + col0) * 128 + kk * 64 + kcb);
#pragma unroll
      for (int kk = 0; kk < 2; ++kk)
#pragma unroll
        for (int m = 0; m < 4; ++m)
#pragma unroll
          for (int n = 0; n < 2; ++n)
            acc[which][m][n] = __builtin_amdgcn_mfma_f32_16x16x32_bf16(
                af[m][kk], bfr[n][kk], acc[which][m][n], 0, 0, 0);
    }
    __syncthreads();
  }

#pragma unroll
  for (int which = 0; which < 3; ++which) {
    const float* bias = (which == 0) ? bk : (which == 1) ? bq : bv;
    if (which == 0) {
#pragma unroll
      for (int n = 0; n < 2; ++n) {
        int nl = wc * 32 + n * 16 + col0;
        float bs = bias[nl];
#pragma unroll
        for (int m = 0; m < 4; ++m)
#pragma unroll
          for (int r = 0; r < 4; ++r) {
            int t = m0 + wr * 64 + m * 16 + rg * 4 + r;
            float x = acc[0][m][n][r] + bs;
            Kb[(size_t)t * Hn + nl] = f2bf(x / (1.f + __expf(-x)));
          }
      }
    } else {
      u16* dst = (which == 1) ? QT : VT;
#pragma unroll
      for (int n = 0; n < 2; ++n) {
        int nl = wc * 32 + n * 16 + col0;
        float bs = bias[nl];
#pragma unroll
        for (int m = 0; m < 4; ++m) {
          int t0 = m0 + wr * 64 + m * 16 + rg * 4;
          int bb = t0 >> 9, tt = t0 & (Tn - 1);
          ushort4 o;
#pragma unroll
          for (int r = 0; r < 4; ++r) {
            float x = acc[which][m][n][r] + bs;
            ((u16*)&o)[r] = f2bf(x / (1.f + __expf(-x)));
          }
          *(ushort4*)&dst[((size_t)bb * Hn + nl) * Tn + tt] = o;
        }
      }
    }
  }
}

// ---------- stage 2: Q2 = (dagT @ Q)/sqrt(H) ----------  grid (4, B)
__global__ __launch_bounds__(256) void dagq_tiled(
    const u16* __restrict__ dagT, const u16* __restrict__ QT,
    u16* __restrict__ Q2) {
  __shared__ u16 sm[16384];
  int b = blockIdx.y, m0 = blockIdx.x * 128;
  f32x4 acc[4][4] = {};
  gemm_core(dagT + (size_t)m0 * Tn, Tn, QT + (size_t)b * Hn * Tn, Tn, Tn, sm, acc);

  const float scale = 0.08838834764831845f;
  int lane = threadIdx.x & 63, wave = threadIdx.x >> 6;
  int wr = wave >> 1, wc = wave & 1;
  int col0 = lane & 15, rg = lane >> 4;
#pragma unroll
  for (int n = 0; n < 4; ++n) {
    int h = wc * 64 + n * 16 + col0;
#pragma unroll
    for (int m = 0; m < 4; ++m)
#pragma unroll
      for (int r = 0; r < 4; ++r) {
        int i = m0 + wr * 64 + m * 16 + rg * 4 + r;
        Q2[((size_t)b * Tn + i) * Hn + h] = f2bf(acc[m][n][r] * scale);
      }
  }
}

// ---------- stage 3+4 fused: S=Q2 K^T, mask, softmax, P=probs+dag, O=P@V ----------
// grid (4, B), 512 threads (8 waves: wr in {0,1}, wc in {0..3}).
__global__ __launch_bounds__(512, 2) void attn_out(
    const u16* __restrict__ Q2, const u16* __restrict__ Kb,
    const u64* __restrict__ dbits, const u16* __restrict__ VT,
    float* __restrict__ O) {
  __shared__ u16 smP[128 * 128];     // 32KB: Q2 tile, then P chunks (swizzled)
  __shared__ u64 smB[128 * 8];       // 8KB mask bits
  __shared__ float red_max[128][4];
  __shared__ float red_sum[128][4];

  int b = blockIdx.y, m0 = blockIdx.x * 128;
  int tid = threadIdx.x, lane = tid & 63, wave = tid >> 6;
  int wr = wave >> 2, wc = wave & 3;
  int col0 = lane & 15, rg = lane >> 4, kcb = rg * 16;

  // stage Q2 tile (128x128 = 32KB)
  const char* A0 = (const char*)(Q2 + ((size_t)b * Tn + m0) * Hn);
#pragma unroll
  for (int q = 0; q < 4; ++q) {
    int chunk = q * 8 + wave;
    int flat = chunk * 1024 + lane * 16;
    int row = flat >> 8, colb = flat & 255;
    gload16(A0 + (size_t)row * 256 + colb, (char*)smP + chunk * 1024);
  }
  gload16((const char*)dbits + (size_t)m0 * 64 + wave * 1024 + lane * 16,
          (char*)smB + wave * 1024);
  __syncthreads();

  // S = Q2 K^T (rows wr*64.., cols wc*128..)
  f32x4 acc[4][8] = {};
  const char* Kbase = (const char*)(Kb + (size_t)b * Tn * Hn);
#pragma unroll
  for (int kk = 0; kk < 4; ++kk) {
    bf16x8 af[4], bfr[8];
#pragma unroll
    for (int m = 0; m < 4; ++m)
      af[m] = *(const bf16x8*)((char*)smP + (wr * 64 + m * 16 + col0) * 256 + kk * 64 + kcb);
#pragma unroll
    for (int nf = 0; nf < 8; ++nf)
      bfr[nf] = *(const bf16x8*)(Kbase + (size_t)(wc * 128 + nf * 16 + col0) * 256 + kk * 64 + kcb);
#pragma unroll
    for (int m = 0; m < 4; ++m)
#pragma unroll
      for (int nf = 0; nf < 8; ++nf)
        acc[m][nf] = __builtin_amdgcn_mfma_f32_16x16x32_bf16(af[m], bfr[nf], acc[m][nf], 0, 0, 0);
  }

  // mask + row max
  float rmax[4][4];
#pragma unroll
  for (int m = 0; m < 4; ++m)
#pragma unroll
    for (int r = 0; r < 4; ++r) {
      int rl = wr * 64 + m * 16 + rg * 4 + r;
      u64 w0 = smB[rl * 8 + wc * 2 + 0];
      u64 w1 = smB[rl * 8 + wc * 2 + 1];
      float mx = -INFINITY;
#pragma unroll
      for (int nf = 0; nf < 8; ++nf) {
        u64 w = (nf < 4) ? w0 : w1;
        int bp = (nf & 3) * 16 + col0;
        float v = ((w >> bp) & 1) ? acc[m][nf][r] : -INFINITY;
        acc[m][nf][r] = v;
        mx = fmaxf(mx, v);
      }
      rmax[m][r] = mx;
    }
#pragma unroll
  for (int s = 1; s < 16; s <<= 1)
#pragma unroll
    for (int m = 0; m < 4; ++m)
#pragma unroll
      for (int r = 0; r < 4; ++r)
        rmax[m][r] = fmaxf(rmax[m][r], __shfl_xor(rmax[m][r], s, 64));
  if (col0 == 0)
#pragma unroll
    for (int m = 0; m < 4; ++m)
#pragma unroll
      for (int r = 0; r < 4; ++r)
        red_max[wr * 64 + m * 16 + rg * 4 + r][wc] = rmax[m][r];
  __syncthreads();

  // exp + row sum
  float rsum[4][4];
#pragma unroll
  for (int m = 0; m < 4; ++m)
#pragma unroll
    for (int r = 0; r < 4; ++r) {
      int rl = wr * 64 + m * 16 + rg * 4 + r;
      float mm = fmaxf(fmaxf(red_max[rl][0], red_max[rl][1]),
                       fmaxf(red_max[rl][2], red_max[rl][3]));
      float rowmax = (mm == -INFINITY) ? 0.f : mm;
      float s = 0.f;
#pragma unroll
      for (int nf = 0; nf < 8; ++nf) {
        float v = acc[m][nf][r];
        float e = (v == -INFINITY) ? 0.f : __expf(v - rowmax);
        acc[m][nf][r] = e;
        s += e;
      }
      rsum[m][r] = s;
    }
#pragma unroll
  for (int s = 1; s < 16; s <<= 1)
#pragma unroll
    for (int m = 0; m < 4; ++m)
#pragma unroll
      for (int r = 0; r < 4; ++r)
        rsum[m][r] += __shfl_xor(rsum[m][r], s, 64);
  if (col0 == 0)
#pragma unroll
    for (int m = 0; m < 4; ++m)
#pragma unroll
      for (int r = 0; r < 4; ++r)
        red_sum[wr * 64 + m * 16 + rg * 4 + r][wc] = rsum[m][r];
  __syncthreads();

  // normalize in place (P = probs; +dag added at LDS write)
#pragma unroll
  for (int m = 0; m < 4; ++m)
#pragma unroll
    for (int r = 0; r < 4; ++r) {
      int rl = wr * 64 + m * 16 + rg * 4 + r;
      float s = red_sum[rl][0] + red_sum[rl][1] + red_sum[rl][2] + red_sum[rl][3];
      float inv = (s > 0.f) ? (1.f / s) : 0.f;
#pragma unroll
      for (int nf = 0; nf < 8; ++nf) acc[m][nf][r] *= inv;
    }

  // PV: 4 chunk iterations over k; chunk c = cols c*128..c*128+127 of P
  f32x4 acco[4][2] = {};
  const char* Vb = (const char*)(VT + (size_t)b * Hn * Tn);
  for (int c = 0; c < 4; ++c) {
    __syncthreads();                 // smP free (Q2/prev chunk reads done)
    if (wc == c) {
#pragma unroll
      for (int m = 0; m < 4; ++m)
#pragma unroll
        for (int r = 0; r < 4; ++r) {
          int rl = wr * 64 + m * 16 + rg * 4 + r;
          u64 w0 = smB[rl * 8 + wc * 2 + 0];
          u64 w1 = smB[rl * 8 + wc * 2 + 1];
          int sw = (rl & 7) << 4;
#pragma unroll
          for (int nf = 0; nf < 8; ++nf) {
            u64 w = (nf < 4) ? w0 : w1;
            int bp = (nf & 3) * 16 + col0;
            float p = acc[m][nf][r] + (float)((w >> bp) & 1);
            int byte = rl * 256 + (((nf * 16 + col0) * 2) ^ sw);
            *(u16*)((char*)smP + byte) = f2bf(p);
          }
        }
    }
    __syncthreads();
#pragma unroll
    for (int kk = 0; kk < 4; ++kk) {
      bf16x8 pa[4], vb[2];
#pragma unroll
      for (int m = 0; m < 4; ++m) {
        int row = wr * 64 + m * 16 + col0;
        pa[m] = *(const bf16x8*)((char*)smP + row * 256 + ((kk * 64 + kcb) ^ ((row & 7) << 4)));
      }
#pragma unroll
      for (int n = 0; n < 2; ++n)
        vb[n] = *(const bf16x8*)(Vb + (size_t)(wc * 32 + n * 16 + col0) * 1024 + c * 256 + kk * 64 + kcb);
#pragma unroll
      for (int m = 0; m < 4; ++m)
#pragma unroll
        for (int n = 0; n < 2; ++n)
          acco[m][n] = __builtin_amdgcn_mfma_f32_16x16x32_bf16(pa[m], vb[n], acco[m][n], 0, 0, 0);
    }
  }

  // epilogue: O fp32 [B,T,H]
#pragma unroll
  for (int m = 0; m < 4; ++m)
#pragma unroll
    for (int n = 0; n < 2; ++n)
#pragma unroll
      for (int r = 0; r < 4; ++r) {
        int i = m0 + wr * 64 + m * 16 + rg * 4 + r;
        O[((size_t)b * Tn + i) * Hn + wc * 32 + n * 16 + col0] = acco[m][n][r];
      }
}

extern "C" void kernel_launch(void* const* d_in, const int* in_sizes, int n_in,
                              void* d_out, int out_size, void* d_ws, size_t ws_size,
                              hipStream_t stream) {
  const float* X   = (const float*)d_in[0];
  const float* dag = (const float*)d_in[1];
  const float* Wk  = (const float*)d_in[2];
  const float* bk  = (const float*)d_in[3];
  const float* Wq  = (const float*)d_in[4];
  const float* bq  = (const float*)d_in[5];
  const float* Wv  = (const float*)d_in[6];
  const float* bv  = (const float*)d_in[7];
  float* O = (float*)d_out;

  char* ws = (char*)d_ws;
  u16* Xb   = (u16*)(ws);                 // 33,554,432 B
  u16* Wcat = (u16*)(ws + 33554432);      //    393,216
  u16* dagT = (u16*)(ws + 33947648);      //    524,288
  u64* dbits= (u64*)(ws + 34471936);      //     32,768
  u16* Kb   = (u16*)(ws + 34504704);      //  8,388,608
  u16* QT   = (u16*)(ws + 42893312);      //  8,388,608
  u16* VT   = (u16*)(ws + 51281920);      //  8,388,608
  u16* Q2   = (u16*)(ws + 59670528);      //  8,388,608  (end 68,059,136)

  conv_f2b<<<(BT * Dn / 4) / 256, 256, 0, stream>>>((const float4*)X, (ushort4*)Xb);
  conv_f2b<<<(Hn * Dn / 4) / 256, 256, 0, stream>>>((const float4*)Wk, (ushort4*)Wcat);
  conv_f2b<<<(Hn * Dn / 4) / 256, 256, 0, stream>>>((const float4*)Wq, (ushort4*)(Wcat + Hn * Dn));
  conv_f2b<<<(Hn * Dn / 4) / 256, 256, 0, stream>>>((const float4*)Wv, (ushort4*)(Wcat + 2 * Hn * Dn));
  dag_tr<<<64, 256, 0, stream>>>(dag, dagT);
  dag_bits<<<16, 256, 0, stream>>>(dagT, dbits);

  qkv3<<<BT / 128, 512, 0, stream>>>(Xb, Wcat, bk, bq, bv, Kb, QT, VT);
  dagq_tiled<<<dim3(Tn / 128, Bn), 256, 0, stream>>>(dagT, QT, Q2);
  attn_out<<<dim3(Tn / 128, Bn), 512, 0, stream>>>(Q2, Kb, dbits, VT, O);
}

// Round 5
// 117.184 us; speedup vs baseline: 1.7330x; 1.7330x over previous
//
#include <hip/hip_runtime.h>
#include <hip/hip_bf16.h>

#define Bn 64
#define Tn 512
#define Dn 512
#define Hn 128
#define BT (Bn*Tn)

typedef unsigned short u16;
typedef unsigned long long u64;
typedef __attribute__((ext_vector_type(8))) short bf16x8;
typedef __attribute__((ext_vector_type(4))) float f32x4;

__device__ __forceinline__ u16 f2bf(float f) {
  union { float f; unsigned u; } v; v.f = f;
  unsigned r = (v.u + 0x7FFFu + ((v.u >> 16) & 1u)) >> 16;
  return (u16)r;
}

__device__ __forceinline__ bf16x8 pack8(float4 a, float4 b) {
  bf16x8 o;
  o[0] = (short)f2bf(a.x); o[1] = (short)f2bf(a.y);
  o[2] = (short)f2bf(a.z); o[3] = (short)f2bf(a.w);
  o[4] = (short)f2bf(b.x); o[5] = (short)f2bf(b.y);
  o[6] = (short)f2bf(b.z); o[7] = (short)f2bf(b.w);
  return o;
}

// async global->LDS, 16B/lane; LDS dest = wave-uniform base (+lane*16 by HW)
__device__ __forceinline__ void gload16(const void* g, void* lds) {
  __builtin_amdgcn_global_load_lds(
      (const __attribute__((address_space(1))) unsigned int*)g,
      (__attribute__((address_space(3))) unsigned int*)lds, 16, 0, 0);
}

// ---------- small prep kernels ----------
__global__ __launch_bounds__(256) void conv_f2b(const float4* __restrict__ in,
                                                ushort4* __restrict__ out) {
  int idx = blockIdx.x * 256 + threadIdx.x;
  float4 v = in[idx];
  ushort4 o; o.x = f2bf(v.x); o.y = f2bf(v.y); o.z = f2bf(v.z); o.w = f2bf(v.w);
  out[idx] = o;
}

// coalesced LDS-tiled transpose: dagT[i*T+k] = bf16(dag[k*T+i])
__global__ __launch_bounds__(256) void dag_tr(const float* __restrict__ dag,
                                              u16* __restrict__ dagT) {
  __shared__ float s[64][65];
  int bx = blockIdx.x & 7, by = blockIdx.x >> 3;
  int r0 = by * 64, c0 = bx * 64;
  int t = threadIdx.x;
  int c4 = t & 15, rr = t >> 4;
#pragma unroll
  for (int q = 0; q < 4; ++q) {
    int r = rr + q * 16;
    float4 v = *(const float4*)&dag[(size_t)(r0 + r) * Tn + c0 + c4 * 4];
    s[c4 * 4 + 0][r] = v.x; s[c4 * 4 + 1][r] = v.y;
    s[c4 * 4 + 2][r] = v.z; s[c4 * 4 + 3][r] = v.w;
  }
  __syncthreads();
#pragma unroll
  for (int q = 0; q < 4; ++q) {
    int il = rr + q * 16;
    ushort4 o;
    o.x = f2bf(s[il][c4 * 4 + 0]); o.y = f2bf(s[il][c4 * 4 + 1]);
    o.z = f2bf(s[il][c4 * 4 + 2]); o.w = f2bf(s[il][c4 * 4 + 3]);
    *(ushort4*)&dagT[(size_t)(c0 + il) * Tn + r0 + c4 * 4] = o;
  }
}

// bits[i*8+w] bit j = (dagT[i*T + w*64 + j] != 0)
__global__ __launch_bounds__(256) void dag_bits(const u16* __restrict__ dagT,
                                                u64* __restrict__ bits) {
  int idx = blockIdx.x * 256 + threadIdx.x;
  int i = idx >> 3, w = idx & 7;
  const u16* p = dagT + (size_t)i * Tn + w * 64;
  u64 m = 0;
#pragma unroll
  for (int j = 0; j < 64; ++j) m |= (u64)(p[j] != 0) << j;
  bits[idx] = m;
}

// ---------- 128x128-tile GEMM core (BK=64), 256 threads, swizzled LDS ----------
__device__ __forceinline__ void gemm_core(const u16* __restrict__ A0, int lda,
                                          const u16* __restrict__ B0, int ldb,
                                          int K, u16* sm, f32x4 (&acc)[4][4]) {
  const int tid = threadIdx.x;
  const int lane = tid & 63, wave = tid >> 6;
  const int wr = wave >> 1, wc = wave & 1;
  const int col0 = lane & 15;
  const int kcb = (lane >> 4) * 16;
  const int swl = (col0 & 7) << 4;             // read-side swizzle
  const int arow = wr * 64 + col0;
  const int brow = wc * 64 + col0;
  const char* Ab = (const char*)A0;
  const char* Bb = (const char*)B0;
  char* smb = (char*)sm;

  for (int kt = 0; kt < K; kt += 64) {
#pragma unroll
    for (int q = 0; q < 4; ++q) {
      int flat = wave * 4096 + q * 1024 + lane * 16;
      int row = flat >> 7, colb = flat & 127;
      int sw = (row & 7) << 4;                 // pre-swizzled source
      gload16(Ab + (size_t)row * (lda * 2) + kt * 2 + (colb ^ sw),
              smb + wave * 4096 + q * 1024);
      gload16(Bb + (size_t)row * (ldb * 2) + kt * 2 + (colb ^ sw),
              smb + 16384 + wave * 4096 + q * 1024);
    }
    __syncthreads();
    bf16x8 af[4][2], bfr[4][2];
#pragma unroll
    for (int m = 0; m < 4; ++m)
#pragma unroll
      for (int kk = 0; kk < 2; ++kk) {
        af[m][kk] = *(const bf16x8*)(smb + (arow + m * 16) * 128 + ((kk * 64 + kcb) ^ swl));
        bfr[m][kk] = *(const bf16x8*)(smb + 16384 + (brow + m * 16) * 128 + ((kk * 64 + kcb) ^ swl));
      }
#pragma unroll
    for (int kk = 0; kk < 2; ++kk)
#pragma unroll
      for (int m = 0; m < 4; ++m)
#pragma unroll
        for (int n = 0; n < 4; ++n)
          acc[m][n] = __builtin_amdgcn_mfma_f32_16x16x32_bf16(af[m][kk], bfr[n][kk],
                                                              acc[m][n], 0, 0, 0);
    __syncthreads();
  }
}

// ---------- stage 1: K,Q,V = swish(X W^T + b), fp32 X converted in-kernel ----------
// grid BT/128, 512 threads (8 waves: wr in {0,1}, wc in {0..3}).
__global__ __launch_bounds__(512, 2) void qkv3(
    const float* __restrict__ X, const u16* __restrict__ Wcat,
    const float* __restrict__ bk, const float* __restrict__ bq,
    const float* __restrict__ bv,
    u16* __restrict__ Kb, u16* __restrict__ QT, u16* __restrict__ VT) {
  __shared__ u16 sm[32768];   // 64KB: A(16KB) | Bk | Bq | Bv
  int m0 = blockIdx.x * 128;
  int tid = threadIdx.x, lane = tid & 63, wave = tid >> 6;
  int wr = wave >> 2, wc = wave & 3;
  int col0 = lane & 15, rg = lane >> 4, kcb = rg * 16;
  int swl = (col0 & 7) << 4;
  int xrow = tid >> 2, xcq = tid & 3;      // X staging: row, 16-elem quarter
  f32x4 acc[3][4][2] = {};
  const char* Wb = (const char*)Wcat;
  char* smb = (char*)sm;

  for (int kt = 0; kt < Dn; kt += 64) {
    // A: reg-stage X fp32 -> bf16, swizzled LDS write
    {
      const float4* src = (const float4*)(X + (size_t)(m0 + xrow) * Dn + kt + xcq * 16);
      float4 a0 = src[0], a1 = src[1], a2 = src[2], a3 = src[3];
      int sw = (xrow & 7) << 4;
      *(bf16x8*)(smb + xrow * 128 + ((xcq * 32) ^ sw)) = pack8(a0, a1);
      *(bf16x8*)(smb + xrow * 128 + ((xcq * 32 + 16) ^ sw)) = pack8(a2, a3);
    }
    // W: 48KB via gload16, pre-swizzled source
#pragma unroll
    for (int q = 0; q < 6; ++q) {
      int c2 = wave * 6 + q;
      int which = c2 >> 4, idx = c2 & 15;
      int flat = idx * 1024 + lane * 16;
      int row = flat >> 7, colb = flat & 127;
      int sw = (row & 7) << 4;
      gload16(Wb + (size_t)which * 131072 + (size_t)row * 1024 + (kt << 1) + (colb ^ sw),
              smb + 16384 + which * 16384 + idx * 1024);
    }
    __syncthreads();
    bf16x8 af[4][2];
#pragma unroll
    for (int m = 0; m < 4; ++m)
#pragma unroll
      for (int kk = 0; kk < 2; ++kk)
        af[m][kk] = *(const bf16x8*)(smb + (wr * 64 + m * 16 + col0) * 128 + ((kk * 64 + kcb) ^ swl));
#pragma unroll
    for (int which = 0; which < 3; ++which) {
      bf16x8 bfr[2][2];
#pragma unroll
      for (int n = 0; n < 2; ++n)
#pragma unroll
        for (int kk = 0; kk < 2; ++kk)
          bfr[n][kk] = *(const bf16x8*)(smb + 16384 + which * 16384 +
                                        (wc * 32 + n * 16 + col0) * 128 + ((kk * 64 + kcb) ^ swl));
#pragma unroll
      for (int kk = 0; kk < 2; ++kk)
#pragma unroll
        for (int m = 0; m < 4; ++m)
#pragma unroll
          for (int n = 0; n < 2; ++n)
            acc[which][m][n] = __builtin_amdgcn_mfma_f32_16x16x32_bf16(
                af[m][kk], bfr[n][kk], acc[which][m][n], 0, 0, 0);
    }
    __syncthreads();
  }

#pragma unroll
  for (int which = 0; which < 3; ++which) {
    const float* bias = (which == 0) ? bk : (which == 1) ? bq : bv;
    if (which == 0) {
#pragma unroll
      for (int n = 0; n < 2; ++n) {
        int nl = wc * 32 + n * 16 + col0;
        float bs = bias[nl];
#pragma unroll
        for (int m = 0; m < 4; ++m)
#pragma unroll
          for (int r = 0; r < 4; ++r) {
            int t = m0 + wr * 64 + m * 16 + rg * 4 + r;
            float x = acc[0][m][n][r] + bs;
            Kb[(size_t)t * Hn + nl] = f2bf(x / (1.f + __expf(-x)));
          }
      }
    } else {
      u16* dst = (which == 1) ? QT : VT;
#pragma unroll
      for (int n = 0; n < 2; ++n) {
        int nl = wc * 32 + n * 16 + col0;
        float bs = bias[nl];
#pragma unroll
        for (int m = 0; m < 4; ++m) {
          int t0 = m0 + wr * 64 + m * 16 + rg * 4;
          int bb = t0 >> 9, tt = t0 & (Tn - 1);
          ushort4 o;
#pragma unroll
          for (int r = 0; r < 4; ++r) {
            float x = acc[which][m][n][r] + bs;
            ((u16*)&o)[r] = f2bf(x / (1.f + __expf(-x)));
          }
          *(ushort4*)&dst[((size_t)bb * Hn + nl) * Tn + tt] = o;
        }
      }
    }
  }
}

// ---------- stage 2: Q2 = (dagT @ Q)/sqrt(H) ----------  grid (4, B)
__global__ __launch_bounds__(256) void dagq_tiled(
    const u16* __restrict__ dagT, const u16* __restrict__ QT,
    u16* __restrict__ Q2) {
  __shared__ u16 sm[16384];
  int b = blockIdx.y, m0 = blockIdx.x * 128;
  f32x4 acc[4][4] = {};
  gemm_core(dagT + (size_t)m0 * Tn, Tn, QT + (size_t)b * Hn * Tn, Tn, Tn, sm, acc);

  const float scale = 0.08838834764831845f;
  int lane = threadIdx.x & 63, wave = threadIdx.x >> 6;
  int wr = wave >> 1, wc = wave & 1;
  int col0 = lane & 15, rg = lane >> 4;
#pragma unroll
  for (int n = 0; n < 4; ++n) {
    int h = wc * 64 + n * 16 + col0;
#pragma unroll
    for (int m = 0; m < 4; ++m)
#pragma unroll
      for (int r = 0; r < 4; ++r) {
        int i = m0 + wr * 64 + m * 16 + rg * 4 + r;
        Q2[((size_t)b * Tn + i) * Hn + h] = f2bf(acc[m][n][r] * scale);
      }
  }
}

// ---------- stage 3+4: flash-style fused attention + dag-PV ----------
// grid (4, B), 512 threads (8 waves: wr in {0,1}, wc in {0..3}).
// O = (sum_c exp(S_c - m)*V_c)/l + dagT @ V, online softmax over 4 chunks of 128 keys.
__global__ __launch_bounds__(512, 1) void attn_flash(
    const u16* __restrict__ Q2, const u16* __restrict__ Kb,
    const u64* __restrict__ dbits, const u16* __restrict__ VT,
    const u16* __restrict__ dagT, float* __restrict__ O) {
  __shared__ u16 smQ[128 * 128];     // 32KB Q2 tile (swizzled)
  __shared__ u16 smP[128 * 128];     // 32KB per-chunk P (swizzled)
  __shared__ u64 smB[128 * 8];       // 8KB mask bits
  __shared__ float redm[128][4];
  __shared__ float reds[128][4];

  int b = blockIdx.y, m0 = blockIdx.x * 128;
  int tid = threadIdx.x, lane = tid & 63, wave = tid >> 6;
  int wr = wave >> 2, wc = wave & 3;
  int col0 = lane & 15, rg = lane >> 4, kcb = rg * 16;
  int swl = (col0 & 7) << 4;

  // stage Q2 tile (pre-swizzled source) + mask bits
  const char* A0 = (const char*)(Q2 + ((size_t)b * Tn + m0) * Hn);
#pragma unroll
  for (int q = 0; q < 4; ++q) {
    int chunk = q * 8 + wave;
    int flat = chunk * 1024 + lane * 16;
    int row = flat >> 8, colb = flat & 255;
    int sw = (row & 7) << 4;
    gload16(A0 + (size_t)row * 256 + (colb ^ sw), (char*)smQ + chunk * 1024);
  }
  gload16((const char*)dbits + (size_t)m0 * 64 + wave * 1024 + lane * 16,
          (char*)smB + wave * 1024);
  __syncthreads();

  f32x4 acco_e[4][2] = {};
  f32x4 acco_d[4][2] = {};
  float mrun[4][4], lrun[4][4];
#pragma unroll
  for (int m = 0; m < 4; ++m)
#pragma unroll
    for (int r = 0; r < 4; ++r) { mrun[m][r] = -INFINITY; lrun[m][r] = 0.f; }

  const char* Kbase = (const char*)(Kb + (size_t)b * Tn * Hn);
  const char* Vb = (const char*)(VT + (size_t)b * Hn * Tn);
  const char* Db = (const char*)(dagT + (size_t)m0 * Tn);

  for (int c = 0; c < 4; ++c) {
    // ---- S chunk: rows wr*64.., cols c*128 + wc*32 + n*16 ----
    f32x4 acc[4][2] = {};
#pragma unroll
    for (int kk = 0; kk < 4; ++kk) {
      bf16x8 af[4], bfr[2];
#pragma unroll
      for (int m = 0; m < 4; ++m)
        af[m] = *(const bf16x8*)((char*)smQ + (wr * 64 + m * 16 + col0) * 256 + ((kk * 64 + kcb) ^ swl));
#pragma unroll
      for (int n = 0; n < 2; ++n)
        bfr[n] = *(const bf16x8*)(Kbase + (size_t)(c * 128 + wc * 32 + n * 16 + col0) * 256 + kk * 64 + kcb);
#pragma unroll
      for (int m = 0; m < 4; ++m)
#pragma unroll
        for (int n = 0; n < 2; ++n)
          acc[m][n] = __builtin_amdgcn_mfma_f32_16x16x32_bf16(af[m], bfr[n], acc[m][n], 0, 0, 0);
    }

    // ---- mask + per-chunk row max ----
    float cmax[4][4];
#pragma unroll
    for (int m = 0; m < 4; ++m)
#pragma unroll
      for (int r = 0; r < 4; ++r) {
        int rl = wr * 64 + m * 16 + rg * 4 + r;
        u64 w = smB[rl * 8 + c * 2 + (wc >> 1)];
        float mx = -INFINITY;
#pragma unroll
        for (int n = 0; n < 2; ++n) {
          int bp = (wc & 1) * 32 + n * 16 + col0;
          float v = ((w >> bp) & 1) ? acc[m][n][r] : -INFINITY;
          acc[m][n][r] = v;
          mx = fmaxf(mx, v);
        }
        cmax[m][r] = mx;
      }
#pragma unroll
    for (int s = 1; s < 16; s <<= 1)
#pragma unroll
      for (int m = 0; m < 4; ++m)
#pragma unroll
        for (int r = 0; r < 4; ++r)
          cmax[m][r] = fmaxf(cmax[m][r], __shfl_xor(cmax[m][r], s, 64));
    if (col0 == 0)
#pragma unroll
      for (int m = 0; m < 4; ++m)
#pragma unroll
        for (int r = 0; r < 4; ++r)
          redm[wr * 64 + m * 16 + rg * 4 + r][wc] = cmax[m][r];
    __syncthreads();   // A: redm visible; prev-chunk PV reads of smP done

    // ---- online update, exp, P->LDS (swizzled), partial sums ----
    float scale_[4][4], csum[4][4];
#pragma unroll
    for (int m = 0; m < 4; ++m)
#pragma unroll
      for (int r = 0; r < 4; ++r) {
        int rl = wr * 64 + m * 16 + rg * 4 + r;
        float cm = fmaxf(fmaxf(redm[rl][0], redm[rl][1]),
                         fmaxf(redm[rl][2], redm[rl][3]));
        float mnew = fmaxf(mrun[m][r], cm);
        float sc = (mnew == -INFINITY) ? 0.f : __expf(mrun[m][r] - mnew);
        mrun[m][r] = mnew;
        scale_[m][r] = sc;
#pragma unroll
        for (int n = 0; n < 2; ++n) {       // rescale O_e accumulator rows
          acco_e[m][n][r] *= sc;
        }
        float s = 0.f;
        int swr = (rl & 7) << 4;
#pragma unroll
        for (int n = 0; n < 2; ++n) {
          float v = acc[m][n][r];
          float e = (v == -INFINITY) ? 0.f : __expf(v - mnew);
          s += e;
          int cl = wc * 32 + n * 16 + col0;  // chunk-local col
          *(u16*)((char*)smP + rl * 256 + ((cl * 2) ^ swr)) = f2bf(e);
        }
        csum[m][r] = s;
      }
#pragma unroll
    for (int s = 1; s < 16; s <<= 1)
#pragma unroll
      for (int m = 0; m < 4; ++m)
#pragma unroll
        for (int r = 0; r < 4; ++r)
          csum[m][r] += __shfl_xor(csum[m][r], s, 64);
    if (col0 == 0)
#pragma unroll
      for (int m = 0; m < 4; ++m)
#pragma unroll
        for (int r = 0; r < 4; ++r)
          reds[wr * 64 + m * 16 + rg * 4 + r][wc] = csum[m][r];
    __syncthreads();   // B: P + reds visible
#pragma unroll
    for (int m = 0; m < 4; ++m)
#pragma unroll
      for (int r = 0; r < 4; ++r) {
        int rl = wr * 64 + m * 16 + rg * 4 + r;
        float tot = reds[rl][0] + reds[rl][1] + reds[rl][2] + reds[rl][3];
        lrun[m][r] = lrun[m][r] * scale_[m][r] + tot;
      }

    // ---- PV: acco_e += P @ V_c ; acco_d += dag_c @ V_c ----
#pragma unroll
    for (int kk = 0; kk < 4; ++kk) {
      bf16x8 pa[4], pad[4], vb[2];
#pragma unroll
      for (int m = 0; m < 4; ++m) {
        int row = wr * 64 + m * 16 + col0;
        pa[m] = *(const bf16x8*)((char*)smP + row * 256 + ((kk * 64 + kcb) ^ swl));
        pad[m] = *(const bf16x8*)(Db + (size_t)row * 1024 + c * 256 + kk * 64 + kcb);
      }
#pragma unroll
      for (int n = 0; n < 2; ++n)
        vb[n] = *(const bf16x8*)(Vb + (size_t)(wc * 32 + n * 16 + col0) * 1024 + c * 256 + kk * 64 + kcb);
#pragma unroll
      for (int m = 0; m < 4; ++m)
#pragma unroll
        for (int n = 0; n < 2; ++n) {
          acco_e[m][n] = __builtin_amdgcn_mfma_f32_16x16x32_bf16(pa[m], vb[n], acco_e[m][n], 0, 0, 0);
          acco_d[m][n] = __builtin_amdgcn_mfma_f32_16x16x32_bf16(pad[m], vb[n], acco_d[m][n], 0, 0, 0);
        }
    }
  }

  // ---- epilogue: O = acco_e/l + acco_d ----
#pragma unroll
  for (int m = 0; m < 4; ++m)
#pragma unroll
    for (int r = 0; r < 4; ++r) {
      float l = lrun[m][r];
      float inv = (l > 0.f) ? (1.f / l) : 0.f;
      int i = m0 + wr * 64 + m * 16 + rg * 4 + r;
#pragma unroll
      for (int n = 0; n < 2; ++n)
        O[((size_t)b * Tn + i) * Hn + wc * 32 + n * 16 + col0] =
            acco_e[m][n][r] * inv + acco_d[m][n][r];
    }
}

extern "C" void kernel_launch(void* const* d_in, const int* in_sizes, int n_in,
                              void* d_out, int out_size, void* d_ws, size_t ws_size,
                              hipStream_t stream) {
  const float* X   = (const float*)d_in[0];
  const float* dag = (const float*)d_in[1];
  const float* Wk  = (const float*)d_in[2];
  const float* bk  = (const float*)d_in[3];
  const float* Wq  = (const float*)d_in[4];
  const float* bq  = (const float*)d_in[5];
  const float* Wv  = (const float*)d_in[6];
  const float* bv  = (const float*)d_in[7];
  float* O = (float*)d_out;

  char* ws = (char*)d_ws;
  u16* Wcat = (u16*)(ws);                 //    393,216
  u16* dagT = (u16*)(ws + 393216);        //    524,288
  u64* dbits= (u64*)(ws + 917504);        //     32,768
  u16* Kb   = (u16*)(ws + 950272);        //  8,388,608
  u16* QT   = (u16*)(ws + 9338880);       //  8,388,608
  u16* VT   = (u16*)(ws + 17727488);      //  8,388,608
  u16* Q2   = (u16*)(ws + 26116096);      //  8,388,608  (end 34,504,704)

  conv_f2b<<<(Hn * Dn / 4) / 256, 256, 0, stream>>>((const float4*)Wk, (ushort4*)Wcat);
  conv_f2b<<<(Hn * Dn / 4) / 256, 256, 0, stream>>>((const float4*)Wq, (ushort4*)(Wcat + Hn * Dn));
  conv_f2b<<<(Hn * Dn / 4) / 256, 256, 0, stream>>>((const float4*)Wv, (ushort4*)(Wcat + 2 * Hn * Dn));
  dag_tr<<<64, 256, 0, stream>>>(dag, dagT);
  dag_bits<<<16, 256, 0, stream>>>(dagT, dbits);

  qkv3<<<BT / 128, 512, 0, stream>>>(X, Wcat, bk, bq, bv, Kb, QT, VT);
  dagq_tiled<<<dim3(Tn / 128, Bn), 256, 0, stream>>>(dagT, QT, Q2);
  attn_flash<<<dim3(Tn / 128, Bn), 512, 0, stream>>>(Q2, Kb, dbits, VT, dagT, O);
}